// Round 1
// baseline (483.209 us; speedup 1.0000x reference)
//
#include <hip/hip_runtime.h>
#include <math.h>

// x: [B=16, C=256, H=128, W=128] fp32; plane = 16384 elems; B*C = 4096 planes
#define PLANE 16384
#define NPLANES 4096
#define NB 16
#define NC 256
#define NR 16

typedef float vfloat4 __attribute__((ext_vector_type(4)));

// Kernel 1: per-(b,c) plane mean. 4096 blocks x 256 thr; __launch_bounds__(256,8)
// caps VGPR at 64 -> 8 blocks/CU -> exactly 2 dispatch rounds, no ragged tail.
// Regular (caching) loads on purpose: they populate L3 so the scale pass can
// re-read x from Infinity Cache (x is exactly L3-sized).
__global__ __launch_bounds__(256, 8) void pool_kernel(const float* __restrict__ x,
                                                      float* __restrict__ mean) {
    const size_t base = (size_t)blockIdx.x * PLANE;
    const vfloat4* xp = (const vfloat4*)(x + base);
    const int tid = threadIdx.x;
    float s = 0.f;
    #pragma unroll
    for (int h = 0; h < 2; ++h) {           // 2 x 8-deep load batches (same sum order as before)
        vfloat4 v[8];
        #pragma unroll
        for (int j = 0; j < 8; ++j) v[j] = xp[tid + (h * 8 + j) * 256];
        #pragma unroll
        for (int j = 0; j < 8; ++j) s += (v[j].x + v[j].y) + (v[j].z + v[j].w);
    }
    // wave64 shuffle reduce
    #pragma unroll
    for (int o = 32; o > 0; o >>= 1) s += __shfl_down(s, o, 64);
    __shared__ float wsum[4];
    if ((tid & 63) == 0) wsum[tid >> 6] = s;
    __syncthreads();
    if (tid == 0) {
        mean[blockIdx.x] = ((wsum[0] + wsum[1]) + (wsum[2] + wsum[3])) * (1.0f / (float)PLANE);
    }
}

// Kernel 2 (tiny): one block per batch computes h[16] = relu(w1 @ mean + b1),
// then thread c computes gate[b,c] = sigmoid(b2[c] + sum_r h[r]*w2[c,r]).
// Removes the redundant gate preamble from all 4096 scale blocks.
__global__ __launch_bounds__(256) void gate_kernel(const float* __restrict__ mean,
                                                   const float* __restrict__ w1,
                                                   const float* __restrict__ b1,
                                                   const float* __restrict__ w2,
                                                   const float* __restrict__ b2,
                                                   float* __restrict__ gate) {
    const int b = blockIdx.x;            // 16 blocks
    const int tid = threadIdx.x;
    const int wave = tid >> 6;
    const int lane = tid & 63;

    __shared__ float hsh[NR];
    {
        const vfloat4 yv = ((const vfloat4*)(mean + b * NC))[lane];  // c' = 4*lane..+3
        #pragma unroll
        for (int k = 0; k < 4; ++k) {
            const int r = wave * 4 + k;
            const vfloat4 wv = ((const vfloat4*)(w1 + r * NC))[lane];
            float p = yv.x * wv.x + yv.y * wv.y + yv.z * wv.z + yv.w * wv.w;
            #pragma unroll
            for (int o = 32; o > 0; o >>= 1) p += __shfl_down(p, o, 64);
            if (lane == 0) hsh[r] = fmaxf(p + b1[r], 0.f);
        }
    }
    __syncthreads();
    const int c = tid;                   // 256 channels, one per thread
    float a = b2[c];
    #pragma unroll
    for (int r = 0; r < NR; ++r) a += hsh[r] * w2[c * NR + r];
    gate[b * NC + c] = 1.0f / (1.0f + expf(-a));
}

// Kernel 3: pure stream. Preamble is ONE uniform scalar load of gate[plane].
// Plane mapping is LIFO (most-recently-pooled planes read first, for L3 reuse)
// but XCD-parity-preserving: plane % 8 == blockIdx.x % 8, so any per-XCD L2
// residue from the pool pass stays local. NT stores keep x resident in L3.
__global__ __launch_bounds__(256, 8) void scale_kernel(const float* __restrict__ x,
                                                       const float* __restrict__ gate,
                                                       float* __restrict__ out) {
    const int i = blockIdx.x;
    const int plane = (4088 - (i & ~7)) + (i & 7);   // bijection on [0,4096), LIFO by octet
    const float g = gate[plane];                      // wave-uniform -> s_load
    const size_t base = (size_t)plane * PLANE;
    const vfloat4* xp = (const vfloat4*)(x + base);
    vfloat4* op = (vfloat4*)(out + base);
    const int tid = threadIdx.x;
    #pragma unroll
    for (int h = 0; h < 2; ++h) {
        vfloat4 v[8];
        #pragma unroll
        for (int j = 0; j < 8; ++j) v[j] = xp[tid + (h * 8 + j) * 256];
        #pragma unroll
        for (int j = 0; j < 8; ++j) {
            vfloat4 w = v[j];
            w.x *= g; w.y *= g; w.z *= g; w.w *= g;
            __builtin_nontemporal_store(w, op + tid + (h * 8 + j) * 256);
        }
    }
}

extern "C" void kernel_launch(void* const* d_in, const int* in_sizes, int n_in,
                              void* d_out, int out_size, void* d_ws, size_t ws_size,
                              hipStream_t stream) {
    const float* x  = (const float*)d_in[0];
    const float* w1 = (const float*)d_in[1];
    const float* b1 = (const float*)d_in[2];
    const float* w2 = (const float*)d_in[3];
    const float* b2 = (const float*)d_in[4];
    float* out = (float*)d_out;

    float* mean = (float*)d_ws;          // 4096 floats
    float* gate = mean + NPLANES;        // 4096 floats (ws >= 32 KiB)

    pool_kernel<<<NPLANES, 256, 0, stream>>>(x, mean);
    gate_kernel<<<NB, 256, 0, stream>>>(mean, w1, b1, w2, b2, gate);
    scale_kernel<<<NPLANES, 256, 0, stream>>>(x, gate, out);
}